// Round 1
// baseline (9325.708 us; speedup 1.0000x reference)
//
#include <hip/hip_runtime.h>
#include <cmath>

#define WIN 64
#define HID 512
#define KIN 518   // 512 + 6 logsig channels

struct Sched { int starts[63]; int ends[63]; };

// ---------------------------------------------------------------------------
// Phase 1: Brownian path cumsum + depth-2 logsig (Levy areas) at static indices.
// One thread per batch element; per-thread Levy-area checkpoints at the 20
// possible 'start' indices (multiples of 50) live in LDS.
// ---------------------------------------------------------------------------
__global__ __launch_bounds__(64)
void logsig_kernel(const float* __restrict__ z, float* __restrict__ ls,
                   Sched sc, float scale) {
  __shared__ float Cs[64][20][3];
  const int tid = threadIdx.x;
  const int b = blockIdx.x * 64 + tid;
  const float* zb = z + (size_t)b * 3000;
  float* lsb = ls + (size_t)b * WIN * 6;
#pragma unroll
  for (int c = 0; c < 6; ++c) lsb[c] = 0.f;   // ls[:,0,:] = 0

  float bp0 = 0.f, bp1 = 0.f, bp2 = 0.f;      // bp[0] = 0 (z[:,0] zeroed)
  float C01 = 0.f, C02 = 0.f, C12 = 0.f;      // prefix of cross terms (i < j)
  int ke = 0;
  for (int j = 0; j < 1000; ++j) {
    if ((j % 50) == 0) {
      int s = j / 50;
      Cs[tid][s][0] = C01; Cs[tid][s][1] = C02; Cs[tid][s][2] = C12;
    }
    if (ke < 63 && j == sc.ends[ke]) {
      int s = sc.starts[ke] / 50;   // starts are always multiples of 50
      float* o = lsb + (ke + 1) * 6;
      o[0] = bp0; o[1] = bp1; o[2] = bp2;
      o[3] = C01 - Cs[tid][s][0];
      o[4] = C02 - Cs[tid][s][1];
      o[5] = C12 - Cs[tid][s][2];
      ++ke;
    }
    if (j < 999) {
      float z0 = zb[(j + 1) * 3 + 0] * scale;
      float z1 = zb[(j + 1) * 3 + 1] * scale;
      float z2 = zb[(j + 1) * 3 + 2] * scale;
      float n0 = bp0 + z0, n1 = bp1 + z1, n2 = bp2 + z2;
      C01 += 0.5f * (bp0 * n1 - bp1 * n0);
      C02 += 0.5f * (bp0 * n2 - bp2 * n0);
      C12 += 0.5f * (bp1 * n2 - bp2 * n1);
      bp0 = n0; bp1 = n1; bp2 = n2;
    }
  }
}

// ---------------------------------------------------------------------------
// fp32 TN GEMM: C[m,n] = act( sum_k A[m,k] * W[n,k] + bias[n] )
// BM=32, BN=64, BK=32, 128 threads, 4x4 per thread. Optional secondary A
// source (logsig columns) for k in [K1, K). Optional carry copy (gate).
// ---------------------------------------------------------------------------
__global__ __launch_bounds__(128)
void layer_gemm(const float* __restrict__ A, int lda,
                const float* __restrict__ A2, int lda2, int K1,
                const float* __restrict__ W, int ldw,
                const float* __restrict__ bias,
                float* __restrict__ C, float* __restrict__ C2,
                int K, int act) {
  __shared__ float As[32][36];
  __shared__ float Ws[32][68];
  const int tid = threadIdx.x;
  const int bm = blockIdx.y, bn = blockIdx.x;
  const int kq = tid & 7;       // k-quad within tile
  const int r  = tid >> 3;      // 0..15
  const int nt = tid & 15, mt = tid >> 4;
  const int m0 = mt * 4, n0 = nt * 4;
  float acc[4][4] = {};
  const int nkt = (K + 31) >> 5;

  for (int kt = 0; kt < nkt; ++kt) {
    const int k0 = kt * 32;
    // ---- stage A tile (rows r, r+16) ----
    if (k0 + 32 <= K1) {
#pragma unroll
      for (int rr = 0; rr < 2; ++rr) {
        int m = r + rr * 16;
        const float* p = A + (size_t)(bm * 32 + m) * lda + k0 + kq * 4;
        float4 v = *reinterpret_cast<const float4*>(p);
        As[kq * 4 + 0][m] = v.x; As[kq * 4 + 1][m] = v.y;
        As[kq * 4 + 2][m] = v.z; As[kq * 4 + 3][m] = v.w;
      }
    } else {
#pragma unroll
      for (int rr = 0; rr < 2; ++rr) {
        int m = r + rr * 16, gm = bm * 32 + m;
#pragma unroll
        for (int i = 0; i < 4; ++i) {
          int kg = k0 + kq * 4 + i; float v = 0.f;
          if (kg < K1) v = A[(size_t)gm * lda + kg];
          else if (kg < K) v = A2[(size_t)gm * lda2 + (kg - K1)];
          As[kq * 4 + i][m] = v;
        }
      }
    }
    // ---- stage W tile (rows r, r+16, r+32, r+48) ----
    if (((ldw & 3) == 0) && (k0 + 32 <= K)) {
#pragma unroll
      for (int rr = 0; rr < 4; ++rr) {
        int n = r + rr * 16;
        const float* p = W + (size_t)(bn * 64 + n) * ldw + k0 + kq * 4;
        float4 v = *reinterpret_cast<const float4*>(p);
        Ws[kq * 4 + 0][n] = v.x; Ws[kq * 4 + 1][n] = v.y;
        Ws[kq * 4 + 2][n] = v.z; Ws[kq * 4 + 3][n] = v.w;
      }
    } else {
#pragma unroll
      for (int rr = 0; rr < 4; ++rr) {
        int n = r + rr * 16, gn = bn * 64 + n;
#pragma unroll
        for (int i = 0; i < 4; ++i) {
          int kg = k0 + kq * 4 + i;
          Ws[kq * 4 + i][n] = (kg < K) ? W[(size_t)gn * ldw + kg] : 0.f;
        }
      }
    }
    __syncthreads();
#pragma unroll
    for (int k = 0; k < 32; ++k) {
      float4 av = *reinterpret_cast<const float4*>(&As[k][m0]);
      float4 wv = *reinterpret_cast<const float4*>(&Ws[k][n0]);
      float a[4] = {av.x, av.y, av.z, av.w};
      float w[4] = {wv.x, wv.y, wv.z, wv.w};
#pragma unroll
      for (int i = 0; i < 4; ++i)
#pragma unroll
        for (int j = 0; j < 4; ++j)
          acc[i][j] = fmaf(a[i], w[j], acc[i][j]);
    }
    __syncthreads();
  }
#pragma unroll
  for (int i = 0; i < 4; ++i) {
    int gm = bm * 32 + m0 + i;
#pragma unroll
    for (int j = 0; j < 4; ++j) {
      int gn = bn * 64 + n0 + j;
      float v = acc[i][j] + bias[gn];
      if (act == 1) v = fmaxf(v, 0.f);
      else if (act == 2) v = tanhf(v);
      C[(size_t)gm * HID + gn] = v;
      if (C2) C2[(size_t)gm * HID + gn] = v;
    }
  }
}

// ---------------------------------------------------------------------------
// out[b, t, :] = h[b, :] @ Wout^T   (3 x 512). 4 lanes per row, shfl reduce.
// ---------------------------------------------------------------------------
__global__ __launch_bounds__(256)
void out_kernel(const float* __restrict__ h, const float* __restrict__ Wout,
                float* __restrict__ out, int t) {
  const int tid = threadIdx.x;
  const int lane4 = tid & 3;
  const int row = blockIdx.x * 64 + (tid >> 2);
  const float* hb = h + (size_t)row * HID;
  float a0 = 0.f, a1 = 0.f, a2 = 0.f;
#pragma unroll 4
  for (int q = 0; q < 32; ++q) {
    int k = (q * 4 + lane4) * 4;
    float4 hv = *reinterpret_cast<const float4*>(&hb[k]);
    float4 w0 = *reinterpret_cast<const float4*>(&Wout[k]);
    float4 w1 = *reinterpret_cast<const float4*>(&Wout[512 + k]);
    float4 w2 = *reinterpret_cast<const float4*>(&Wout[1024 + k]);
    a0 += hv.x * w0.x + hv.y * w0.y + hv.z * w0.z + hv.w * w0.w;
    a1 += hv.x * w1.x + hv.y * w1.y + hv.z * w1.z + hv.w * w1.w;
    a2 += hv.x * w2.x + hv.y * w2.y + hv.z * w2.z + hv.w * w2.w;
  }
  a0 += __shfl_xor(a0, 1); a0 += __shfl_xor(a0, 2);
  a1 += __shfl_xor(a1, 1); a1 += __shfl_xor(a1, 2);
  a2 += __shfl_xor(a2, 1); a2 += __shfl_xor(a2, 2);
  if (lane4 == 0) {
    float* o = out + ((size_t)row * WIN + t) * 3;
    o[0] = a0; o[1] = a1; o[2] = a2;
  }
}

// ---------------------------------------------------------------------------
extern "C" void kernel_launch(void* const* d_in, const int* in_sizes, int n_in,
                              void* d_out, int out_size, void* d_ws, size_t ws_size,
                              hipStream_t stream) {
  (void)n_in; (void)out_size; (void)ws_size;
  const float* z    = (const float*)d_in[0];
  const float* W1   = (const float*)d_in[1];
  const float* b1   = (const float*)d_in[2];
  const float* W2   = (const float*)d_in[3];
  const float* b2   = (const float*)d_in[4];
  const float* W3   = (const float*)d_in[5];
  const float* b3   = (const float*)d_in[6];
  const float* Wout = (const float*)d_in[7];
  float* out = (float*)d_out;
  const int B = in_sizes[0] / 3000;   // 1024

  // ---- replicate _static_schedule exactly (numpy linspace doubles) ----
  double tb[1000], tt[64], tu[20];
  {
    double sb = 1.0 / 999.0; for (int i = 0; i < 1000; ++i) tb[i] = i * sb; tb[999] = 1.0;
    double st = 1.0 / 63.0;  for (int k = 0; k < 64; ++k)  tt[k] = k * st;  tt[63] = 1.0;
    for (int j = 0; j < 20; ++j) tu[j] = tb[50 * j];
  }
  auto ssr = [](const double* a, int n, double v) -> int {  // searchsorted right - 1
    int lo = 0, hi = n;
    while (lo < hi) { int mid = (lo + hi) >> 1; if (a[mid] <= v) lo = mid + 1; else hi = mid; }
    return lo - 1;
  };
  Sched sc; int gates[64];
  {
    int u_indices[20];
    for (int j = 0; j < 20; ++j) u_indices[j] = ssr(tb, 1000, tu[j]);
    double u_times[80]; int nut = 0; int last = -1;
    for (int k = 1; k < 64; ++k) {
      int it = ssr(tb, 1000, tt[k]);
      int iu = ssr(tu, 20, tt[k]); if (iu < 0) iu = 0;
      if (iu != last) { u_times[nut++] = tu[iu]; last = iu; }
      sc.starts[k - 1] = u_indices[iu];
      sc.ends[k - 1] = it;
    }
    u_times[nut++] = tt[63];
    int qh = 0;
    for (int k = 0; k < 64; ++k) {
      if (qh < nut && tt[k] >= u_times[qh]) { ++qh; gates[k] = 1; } else gates[k] = 0;
    }
  }

  // ---- workspace carve (f32): ls | carry | a1 | a2 | h3 ----
  float* ls = (float*)d_ws;                      // B x 64 x 6
  float* c  = ls + (size_t)B * WIN * 6;          // B x 512 carry
  float* a1 = c  + (size_t)B * HID;
  float* a2 = a1 + (size_t)B * HID;
  float* h3 = a2 + (size_t)B * HID;

  hipMemsetAsync(c, 0, (size_t)B * HID * sizeof(float), stream);  // h0 = 0
  float scale = (float)std::sqrt(1.0 / 999.0);
  logsig_kernel<<<B / 64, 64, 0, stream>>>(z, ls, sc, scale);

  dim3 grid(HID / 64, B / 32), blk(128);
  for (int t = 0; t < WIN; ++t) {
    layer_gemm<<<grid, blk, 0, stream>>>(c,  HID, ls + t * 6, WIN * 6, HID, W1, KIN, b1, a1, nullptr, KIN, 1);
    layer_gemm<<<grid, blk, 0, stream>>>(a1, HID, nullptr, 0, HID, W2, HID, b2, a2, nullptr, HID, 1);
    layer_gemm<<<grid, blk, 0, stream>>>(a2, HID, nullptr, 0, HID, W3, HID, b3, h3, gates[t] ? c : nullptr, HID, 2);
    out_kernel<<<B / 64, 256, 0, stream>>>(h3, Wout, out, t);
  }
}

// Round 2
// 2494.636 us; speedup vs baseline: 3.7383x; 3.7383x over previous
//
#include <hip/hip_runtime.h>
#include <cmath>

#define WIN 64
#define HID 512
#define BATCH 1024
#define KIN 518
#define CHT 16          // t-chunk for the parallel phase

typedef _Float16 f16;
typedef _Float16 half8 __attribute__((ext_vector_type(8)));
typedef float f32x4 __attribute__((ext_vector_type(4)));

struct Sched { int starts[63]; int ends[63]; };
struct SegMap { int idx[64]; };

// ---------------------------------------------------------------------------
// Brownian cumsum + depth-2 logsig (Levy area) at static indices. (round-1, verified)
// ---------------------------------------------------------------------------
__global__ __launch_bounds__(64)
void logsig_kernel(const float* __restrict__ z, float* __restrict__ ls,
                   Sched sc, float scale) {
  __shared__ float Cs[64][20][3];
  const int tid = threadIdx.x;
  const int b = blockIdx.x * 64 + tid;
  const float* zb = z + (size_t)b * 3000;
  float* lsb = ls + (size_t)b * WIN * 6;
#pragma unroll
  for (int c = 0; c < 6; ++c) lsb[c] = 0.f;
  float bp0 = 0.f, bp1 = 0.f, bp2 = 0.f;
  float C01 = 0.f, C02 = 0.f, C12 = 0.f;
  int ke = 0;
  for (int j = 0; j < 1000; ++j) {
    if ((j % 50) == 0) {
      int s = j / 50;
      Cs[tid][s][0] = C01; Cs[tid][s][1] = C02; Cs[tid][s][2] = C12;
    }
    if (ke < 63 && j == sc.ends[ke]) {
      int s = sc.starts[ke] / 50;
      float* o = lsb + (ke + 1) * 6;
      o[0] = bp0; o[1] = bp1; o[2] = bp2;
      o[3] = C01 - Cs[tid][s][0];
      o[4] = C02 - Cs[tid][s][1];
      o[5] = C12 - Cs[tid][s][2];
      ++ke;
    }
    if (j < 999) {
      float z0 = zb[(j + 1) * 3 + 0] * scale;
      float z1 = zb[(j + 1) * 3 + 1] * scale;
      float z2 = zb[(j + 1) * 3 + 2] * scale;
      float n0 = bp0 + z0, n1 = bp1 + z1, n2 = bp2 + z2;
      C01 += 0.5f * (bp0 * n1 - bp1 * n0);
      C02 += 0.5f * (bp0 * n2 - bp2 * n0);
      C12 += 0.5f * (bp1 * n2 - bp2 * n1);
      bp0 = n0; bp1 = n1; bp2 = n2;
    }
  }
}

// ---------------------------------------------------------------------------
// f32 -> f16 weight convert with K zero-padding.  dst[N][Kd], src[N][Ks].
// ---------------------------------------------------------------------------
__global__ __launch_bounds__(256)
void cvt_w(const float* __restrict__ src, ushort* __restrict__ dst,
           int N, int Ks, int Kd) {
  int i = blockIdx.x * 256 + threadIdx.x;
  int nblk = Kd >> 3;
  if (i >= N * nblk) return;
  int row = i / nblk, k = (i - row * nblk) * 8;
  half8 v;
#pragma unroll
  for (int j = 0; j < 8; ++j) {
    int kk = k + j;
    float f = (kk < Ks) ? src[(size_t)row * Ks + kk] : 0.f;
    v[j] = (f16)f;
  }
  *(half8*)&dst[(size_t)row * Kd + k] = v;
}

// lsh[t][b][64] f16: cols 0..5 = ls[b][t][:], rest 0
__global__ __launch_bounds__(256)
void build_lsh(const float* __restrict__ ls, ushort* __restrict__ lsh) {
  int i = blockIdx.x * 256 + threadIdx.x;   // 65536
  int t = i >> 10, b = i & 1023;
  const float* s = ls + (size_t)b * (WIN * 6) + t * 6;
  half8 v = {}, zz = {};
#pragma unroll
  for (int c = 0; c < 6; ++c) v[c] = (f16)s[c];
  half8* d = (half8*)(lsh + ((size_t)t * BATCH + b) * 64);
  d[0] = v;
#pragma unroll
  for (int q = 1; q < 8; ++q) d[q] = zz;
}

// ---------------------------------------------------------------------------
// fp32 serial GEMM (carry chain): C[m,n] = act(sum_k A[m,k]*W[n,k] + bias[n])
// BM=32, BN=64, 256 threads (4 waves -> 1 wave/SIMD at 256 blocks), 2x4/thread.
// A2 = logsig columns for k in [K1,K). C2h = optional fp16 mirror (Hg16 slot).
// ---------------------------------------------------------------------------
__global__ __launch_bounds__(256)
void sgemm(const float* __restrict__ A, int lda,
           const float* __restrict__ A2, int lda2, int K1,
           const float* __restrict__ W, int ldw,
           const float* __restrict__ bias,
           float* __restrict__ C, ushort* __restrict__ C2h,
           int K, int act) {
  __shared__ float As[32][34];
  __shared__ float Ws[32][68];
  const int tid = threadIdx.x;
  const int bm = blockIdx.y, bn = blockIdx.x;
  const int kq = tid & 7;
  const int ra = tid >> 3;          // 0..31
  const int nt = tid & 15, mt = tid >> 4;
  const int m0 = mt * 2, n0 = nt * 4;
  float acc[2][4] = {};
  const int nkt = (K + 31) >> 5;

  for (int kt = 0; kt < nkt; ++kt) {
    const int k0 = kt * 32;
    if (k0 + 32 <= K1) {
      const float* p = A + (size_t)(bm * 32 + ra) * lda + k0 + kq * 4;
      float4 v = *(const float4*)p;
      As[kq * 4 + 0][ra] = v.x; As[kq * 4 + 1][ra] = v.y;
      As[kq * 4 + 2][ra] = v.z; As[kq * 4 + 3][ra] = v.w;
    } else {
      int gm = bm * 32 + ra;
#pragma unroll
      for (int i2 = 0; i2 < 4; ++i2) {
        int kg = k0 + kq * 4 + i2; float v = 0.f;
        if (kg < K1) v = A[(size_t)gm * lda + kg];
        else if (kg < K) v = A2[(size_t)gm * lda2 + (kg - K1)];
        As[kq * 4 + i2][ra] = v;
      }
    }
    if (((ldw & 3) == 0) && (k0 + 32 <= K)) {
#pragma unroll
      for (int rr = 0; rr < 2; ++rr) {
        int n = ra + rr * 32;
        const float* p = W + (size_t)(bn * 64 + n) * ldw + k0 + kq * 4;
        float4 v = *(const float4*)p;
        Ws[kq * 4 + 0][n] = v.x; Ws[kq * 4 + 1][n] = v.y;
        Ws[kq * 4 + 2][n] = v.z; Ws[kq * 4 + 3][n] = v.w;
      }
    } else {
#pragma unroll
      for (int rr = 0; rr < 2; ++rr) {
        int n = ra + rr * 32, gn = bn * 64 + n;
#pragma unroll
        for (int i2 = 0; i2 < 4; ++i2) {
          int kg = k0 + kq * 4 + i2;
          Ws[kq * 4 + i2][n] = (kg < K) ? W[(size_t)gn * ldw + kg] : 0.f;
        }
      }
    }
    __syncthreads();
#pragma unroll
    for (int k = 0; k < 32; ++k) {
      float2 av = *(const float2*)&As[k][m0];
      float4 wv = *(const float4*)&Ws[k][n0];
      acc[0][0] = fmaf(av.x, wv.x, acc[0][0]);
      acc[0][1] = fmaf(av.x, wv.y, acc[0][1]);
      acc[0][2] = fmaf(av.x, wv.z, acc[0][2]);
      acc[0][3] = fmaf(av.x, wv.w, acc[0][3]);
      acc[1][0] = fmaf(av.y, wv.x, acc[1][0]);
      acc[1][1] = fmaf(av.y, wv.y, acc[1][1]);
      acc[1][2] = fmaf(av.y, wv.z, acc[1][2]);
      acc[1][3] = fmaf(av.y, wv.w, acc[1][3]);
    }
    __syncthreads();
  }
#pragma unroll
  for (int i = 0; i < 2; ++i) {
    int gm = bm * 32 + m0 + i;
#pragma unroll
    for (int j = 0; j < 4; ++j) {
      int gn = bn * 64 + n0 + j;
      float v = acc[i][j] + bias[gn];
      if (act == 1) v = fmaxf(v, 0.f);
      else if (act == 2) v = tanhf(v);
      C[(size_t)gm * HID + gn] = v;
      if (C2h) {
        union { f16 h; ushort u; } cv; cv.h = (f16)v;
        C2h[(size_t)gm * HID + gn] = cv.u;
      }
    }
  }
}

// ---------------------------------------------------------------------------
// fp16 MFMA GEMM (parallel phase): rows = (t_local*1024 + b), 128x128 tile,
// BK=64, 4 waves (2x2), each wave 64x64 via 16x16x32 f16 MFMA.
// Operand order: A-op = W rows (n), B-op = X rows (m) => lane holds 4
// consecutive n for one m  => 8B stores.
// L1 mode: A streamed from per-t carry (Hg16/zero) k<512, lsh tile k-tile 8.
// ---------------------------------------------------------------------------
template<int ACT, int L1>
__global__ __launch_bounds__(256)
void gemm_h(const ushort* __restrict__ A, int lda, int nk,
            const ushort* __restrict__ Hg, const ushort* __restrict__ zeroh,
            const ushort* __restrict__ lsh, int chunk0, SegMap seg,
            const ushort* __restrict__ W, int ldw,
            const float* __restrict__ bias,
            ushort* __restrict__ C, int ldc) {
  __shared__ ushort lds[16384];            // 32KB: X[128][64] | W[128][64]
  char* ldsb = (char*)lds;
  const int tid = threadIdx.x;
  const int wv = tid >> 6, ln = tid & 63;
  const int bn0 = blockIdx.x * 128;
  const int br = blockIdx.y;
  const size_t gr0 = (size_t)br * 128;

  const ushort* abase = A;
  const ushort* lbase = nullptr;
  if (L1) {
    int t = chunk0 + (br >> 3);
    int sj = seg.idx[t];
    abase = (sj < 0) ? zeroh : Hg + (size_t)sj * (BATCH * HID);
    lbase = lsh + (size_t)t * BATCH * 64;
  }

  f32x4 acc[4][4];
#pragma unroll
  for (int mi = 0; mi < 4; ++mi)
#pragma unroll
    for (int ni = 0; ni < 4; ++ni) acc[mi][ni] = (f32x4){0.f, 0.f, 0.f, 0.f};

  const int xr0 = (wv >> 1) * 64, nr0 = (wv & 1) * 64;
  const int l15 = ln & 15, l4 = ln >> 4;

  for (int kt = 0; kt < nk; ++kt) {
    // ---- stage X tile ----
#pragma unroll
    for (int i = 0; i < 4; ++i) {
      int q = (i * 4 + wv) * 64 + ln;
      int r = q >> 3, sl = q & 7, ss = sl ^ (r & 7);
      const ushort* src;
      if (L1) {
        int b_ = ((br & 7) << 7) + r;
        if (kt < 8) src = abase + (size_t)b_ * HID + kt * 64 + ss * 8;
        else        src = lbase + (size_t)b_ * 64 + ss * 8;
      } else {
        src = A + (gr0 + r) * (size_t)lda + kt * 64 + ss * 8;
      }
      __builtin_amdgcn_global_load_lds(
          (const __attribute__((address_space(1))) unsigned int*)src,
          (__attribute__((address_space(3))) unsigned int*)(ldsb + (i * 4 + wv) * 1024),
          16, 0, 0);
    }
    // ---- stage W tile ----
#pragma unroll
    for (int i = 0; i < 4; ++i) {
      int q = (i * 4 + wv) * 64 + ln;
      int r = q >> 3, sl = q & 7, ss = sl ^ (r & 7);
      const ushort* src = W + (size_t)(bn0 + r) * ldw + kt * 64 + ss * 8;
      __builtin_amdgcn_global_load_lds(
          (const __attribute__((address_space(1))) unsigned int*)src,
          (__attribute__((address_space(3))) unsigned int*)(ldsb + 16384 + (i * 4 + wv) * 1024),
          16, 0, 0);
    }
    __syncthreads();
#pragma unroll
    for (int kk = 0; kk < 2; ++kk) {
      half8 xf[4], wf[4];
#pragma unroll
      for (int mi = 0; mi < 4; ++mi) {
        int r = xr0 + mi * 16 + l15;
        int ss = (kk * 4 + l4) ^ (r & 7);
        xf[mi] = *(const half8*)(ldsb + r * 128 + ss * 16);
      }
#pragma unroll
      for (int ni = 0; ni < 4; ++ni) {
        int r = nr0 + ni * 16 + l15;
        int ss = (kk * 4 + l4) ^ (r & 7);
        wf[ni] = *(const half8*)(ldsb + 16384 + r * 128 + ss * 16);
      }
#pragma unroll
      for (int mi = 0; mi < 4; ++mi)
#pragma unroll
        for (int ni = 0; ni < 4; ++ni)
          acc[mi][ni] = __builtin_amdgcn_mfma_f32_16x16x32_f16(wf[ni], xf[mi], acc[mi][ni], 0, 0, 0);
    }
    __syncthreads();
  }
  // ---- epilogue: bias + act + f16 pack, 8B stores ----
#pragma unroll
  for (int mi = 0; mi < 4; ++mi) {
    size_t gm = gr0 + xr0 + mi * 16 + l15;
#pragma unroll
    for (int ni = 0; ni < 4; ++ni) {
      int gn = bn0 + nr0 + ni * 16 + l4 * 4;
      f32x4 a = acc[mi][ni];
      union { f16 h[4]; ushort4 u; } cv;
#pragma unroll
      for (int j = 0; j < 4; ++j) {
        float v = a[j] + bias[gn + j];
        if (ACT == 1) v = fmaxf(v, 0.f);
        else { float xc = fminf(fmaxf(v, -9.f), 9.f); float e = __expf(2.f * xc); v = (e - 1.f) / (e + 1.f); }
        cv.h[j] = (f16)v;
      }
      *(ushort4*)&C[gm * ldc + gn] = cv.u;
    }
  }
}

// ---------------------------------------------------------------------------
// out[b, chunk0+tl, :] = h[row,:] @ Wout^T   (h fp16). 4 lanes/row.
// ---------------------------------------------------------------------------
__global__ __launch_bounds__(256)
void out_k(const ushort* __restrict__ H, const float* __restrict__ Wout,
           float* __restrict__ out, int chunk0) {
  const int tid = threadIdx.x;
  const int lane4 = tid & 3;
  const int row = blockIdx.x * 64 + (tid >> 2);
  const int tl = row >> 10, b = row & 1023;
  const ushort* hb = H + (size_t)row * HID;
  float a0 = 0.f, a1 = 0.f, a2 = 0.f;
#pragma unroll 4
  for (int q = 0; q < 16; ++q) {
    int k = (q * 4 + lane4) * 8;
    half8 hv = *(const half8*)&hb[k];
#pragma unroll
    for (int j = 0; j < 8; ++j) {
      float h = (float)hv[j];
      a0 += h * Wout[k + j];
      a1 += h * Wout[512 + k + j];
      a2 += h * Wout[1024 + k + j];
    }
  }
  a0 += __shfl_xor(a0, 1); a0 += __shfl_xor(a0, 2);
  a1 += __shfl_xor(a1, 1); a1 += __shfl_xor(a1, 2);
  a2 += __shfl_xor(a2, 1); a2 += __shfl_xor(a2, 2);
  if (lane4 == 0) {
    float* o = out + ((size_t)b * WIN + chunk0 + tl) * 3;
    o[0] = a0; o[1] = a1; o[2] = a2;
  }
}

// ---------------------------------------------------------------------------
extern "C" void kernel_launch(void* const* d_in, const int* in_sizes, int n_in,
                              void* d_out, int out_size, void* d_ws, size_t ws_size,
                              hipStream_t stream) {
  (void)n_in; (void)out_size; (void)ws_size; (void)in_sizes;
  const float* z    = (const float*)d_in[0];
  const float* W1   = (const float*)d_in[1];
  const float* b1   = (const float*)d_in[2];
  const float* W2   = (const float*)d_in[3];
  const float* b2   = (const float*)d_in[4];
  const float* W3   = (const float*)d_in[5];
  const float* b3   = (const float*)d_in[6];
  const float* Wout = (const float*)d_in[7];
  float* out = (float*)d_out;

  // ---- replicate _static_schedule exactly (numpy linspace doubles) ----
  double tb[1000], tt[64], tu[20];
  {
    double sb = 1.0 / 999.0; for (int i = 0; i < 1000; ++i) tb[i] = i * sb; tb[999] = 1.0;
    double st = 1.0 / 63.0;  for (int k = 0; k < 64; ++k)  tt[k] = k * st;  tt[63] = 1.0;
    for (int j = 0; j < 20; ++j) tu[j] = tb[50 * j];
  }
  auto ssr = [](const double* a, int n, double v) -> int {
    int lo = 0, hi = n;
    while (lo < hi) { int mid = (lo + hi) >> 1; if (a[mid] <= v) lo = mid + 1; else hi = mid; }
    return lo - 1;
  };
  Sched sc; int gates[64];
  {
    int u_indices[20];
    for (int j = 0; j < 20; ++j) u_indices[j] = ssr(tb, 1000, tu[j]);
    double u_times[80]; int nut = 0; int last = -1;
    for (int k = 1; k < 64; ++k) {
      int it = ssr(tb, 1000, tt[k]);
      int iu = ssr(tu, 20, tt[k]); if (iu < 0) iu = 0;
      if (iu != last) { u_times[nut++] = tu[iu]; last = iu; }
      sc.starts[k - 1] = u_indices[iu];
      sc.ends[k - 1] = it;
    }
    u_times[nut++] = tt[63];
    int qh = 0;
    for (int k = 0; k < 64; ++k) {
      if (qh < nut && tt[k] >= u_times[qh]) { ++qh; gates[k] = 1; } else gates[k] = 0;
    }
  }
  // gated-step list + segment map (carry INPUT at step t = h of last gated < t)
  SegMap seg; int gsteps[64], ng = 0, jlast = -1;
  for (int t = 0; t < WIN; ++t) {
    seg.idx[t] = jlast;
    if (gates[t]) { gsteps[ng] = t; jlast = ng; ++ng; }
  }

  // ---- workspace carve ----
  char* p = (char*)d_ws;
  float* ls    = (float*)p;  p += (size_t)BATCH * WIN * 6 * 4;          // 1.5 MB
  float* ping0 = (float*)p;  p += (size_t)BATCH * HID * 4;              // 2 MB
  float* ping1 = (float*)p;  p += (size_t)BATCH * HID * 4;
  float* sa1   = (float*)p;  p += (size_t)BATCH * HID * 4;
  float* sa2   = (float*)p;  p += (size_t)BATCH * HID * 4;
  ushort* Hg16 = (ushort*)p; p += (size_t)22 * BATCH * HID * 2;         // 23 MB
  ushort* zeroh= (ushort*)p; p += (size_t)BATCH * HID * 2;              // 1 MB
  ushort* lsh  = (ushort*)p; p += (size_t)WIN * BATCH * 64 * 2;         // 8.4 MB
  ushort* W1h  = (ushort*)p; p += (size_t)HID * 576 * 2;
  ushort* W2h  = (ushort*)p; p += (size_t)HID * HID * 2;
  ushort* W3h  = (ushort*)p; p += (size_t)HID * HID * 2;
  ushort* A2h  = (ushort*)p; p += (size_t)CHT * BATCH * HID * 2;        // 16.8 MB
  ushort* A3h  = (ushort*)p; p += (size_t)CHT * BATCH * HID * 2;

  hipMemsetAsync(ping0, 0, (size_t)BATCH * HID * 4, stream);
  hipMemsetAsync(zeroh, 0, (size_t)BATCH * HID * 2, stream);

  float scale = (float)std::sqrt(1.0 / 999.0);
  logsig_kernel<<<BATCH / 64, 64, 0, stream>>>(z, ls, sc, scale);
  build_lsh<<<WIN * BATCH / 256, 256, 0, stream>>>(ls, lsh);
  cvt_w<<<(HID * 72 + 255) / 256, 256, 0, stream>>>(W1, W1h, HID, KIN, 576);
  cvt_w<<<(HID * 64 + 255) / 256, 256, 0, stream>>>(W2, W2h, HID, HID, HID);
  cvt_w<<<(HID * 64 + 255) / 256, 256, 0, stream>>>(W3, W3h, HID, HID, HID);

  // ---- serial carry chain over gated steps (last gated h is never read) ----
  float* bufs[2] = {ping0, ping1};
  dim3 sg(8, 32), sb(256);
  for (int j = 0; j < ng - 1; ++j) {
    int g = gsteps[j];
    float* cin  = bufs[j & 1];
    float* cout = bufs[(j + 1) & 1];
    sgemm<<<sg, sb, 0, stream>>>(cin, HID, ls + g * 6, WIN * 6, HID, W1, KIN, b1, sa1, nullptr, KIN, 1);
    sgemm<<<sg, sb, 0, stream>>>(sa1, HID, nullptr, 0, HID, W2, HID, b2, sa2, nullptr, HID, 1);
    sgemm<<<sg, sb, 0, stream>>>(sa2, HID, nullptr, 0, HID, W3, HID, b3, cout,
                                 Hg16 + (size_t)j * BATCH * HID, HID, 2);
  }

  // ---- parallel recompute of all 64 timesteps, fp16 MFMA, t-chunked ----
  dim3 gg(4, CHT * 8), gb(256);
  for (int c = 0; c < WIN / CHT; ++c) {
    int chunk0 = c * CHT;
    gemm_h<1, 1><<<gg, gb, 0, stream>>>(A2h, HID, 9, Hg16, zeroh, lsh, chunk0, seg,
                                        W1h, 576, b1, A2h, HID);
    gemm_h<1, 0><<<gg, gb, 0, stream>>>(A2h, HID, 8, Hg16, zeroh, lsh, chunk0, seg,
                                        W2h, HID, b2, A3h, HID);
    gemm_h<2, 0><<<gg, gb, 0, stream>>>(A3h, HID, 8, Hg16, zeroh, lsh, chunk0, seg,
                                        W3h, HID, b3, A2h, HID);
    out_k<<<CHT * BATCH / 64, 256, 0, stream>>>(A2h, Wout, out, chunk0);
  }
}

// Round 3
// 1074.956 us; speedup vs baseline: 8.6754x; 2.3207x over previous
//
#include <hip/hip_runtime.h>
#include <cmath>

#define WIN 64
#define HID 512
#define BATCH 1024
#define KIN 518
#define CHT 16          // t-chunk for the parallel phase

typedef _Float16 f16;
typedef _Float16 half8 __attribute__((ext_vector_type(8)));
typedef float f32x4 __attribute__((ext_vector_type(4)));

struct Sched { int starts[63]; int ends[63]; };
struct SegMap { int idx[64]; };

// ---------------------------------------------------------------------------
// Builder: dense per-position flag tables for the scan kernel.
// fe[p] = k if p == ends[k] else -1;  sidx[k] = starts[k]/50.
// ---------------------------------------------------------------------------
__global__ __launch_bounds__(1024)
void build_flags(int* __restrict__ fe, int* __restrict__ sidx, Sched sc) {
  int tid = threadIdx.x;
  if (tid < 1000) fe[tid] = -1;
  __syncthreads();
  if (tid < 63) {
    fe[sc.ends[tid]] = tid;
    sidx[tid] = sc.starts[tid] / 50;
  }
}

// ---------------------------------------------------------------------------
// Parallel logsig: one block per batch element. Associative scan of
// (displacement, Levy area) with (d1,A1)o(d2,A2) = (d1+d2, A1+A2+0.5 d1 x d2).
// Writes lsh[t][b][64] fp16 (cols 0..5 = logsig, rest 0) directly.
// ---------------------------------------------------------------------------
__global__ __launch_bounds__(256)
void logsig_scan(const float* __restrict__ z, const int* __restrict__ fe,
                 const int* __restrict__ sidx, ushort* __restrict__ lsh,
                 float scale) {
  __shared__ float zs[3000];
  __shared__ float Cs[20][3];
  __shared__ float wtot[4][6];
  __shared__ float earr[63][6];
  const int tid = threadIdx.x;
  const int b = blockIdx.x;
  const int ln = tid & 63, wv = tid >> 6;

  // stage z row (12 KB, coalesced float4)
  const float4* zrow = (const float4*)(z + (size_t)b * 3000);
  for (int i = tid; i < 750; i += 256) ((float4*)zs)[i] = zrow[i];
  if (tid == 0) { Cs[0][0] = 0.f; Cs[0][1] = 0.f; Cs[0][2] = 0.f; }

  // per-position end flags (global, tiny, L2)
  const int p0 = 4 * tid + 1;
  int myfe[4];
#pragma unroll
  for (int i = 0; i < 4; ++i) myfe[i] = (p0 + i <= 999) ? fe[p0 + i] : -1;
  __syncthreads();

  // ---- local (d, A) over <=4 increments ----
  float d0 = 0.f, d1 = 0.f, d2 = 0.f, A0 = 0.f, A1 = 0.f, A2 = 0.f;
  if (p0 <= 999) {
    float b0 = 0.f, b1 = 0.f, b2 = 0.f;
#pragma unroll
    for (int i = 0; i < 4; ++i) {
      int p = p0 + i;
      if (p > 999) break;
      float n0 = b0 + zs[p * 3 + 0] * scale;
      float n1 = b1 + zs[p * 3 + 1] * scale;
      float n2 = b2 + zs[p * 3 + 2] * scale;
      A0 += 0.5f * (b0 * n1 - b1 * n0);
      A1 += 0.5f * (b0 * n2 - b2 * n0);
      A2 += 0.5f * (b1 * n2 - b2 * n1);
      b0 = n0; b1 = n1; b2 = n2;
    }
    d0 = b0; d1 = b1; d2 = b2;
  }

  // ---- wave inclusive scan (Hillis-Steele, non-commutative assoc op) ----
#pragma unroll
  for (int off = 1; off < 64; off <<= 1) {
    float e0 = __shfl(d0, ln - off), e1 = __shfl(d1, ln - off), e2 = __shfl(d2, ln - off);
    float eA0 = __shfl(A0, ln - off), eA1 = __shfl(A1, ln - off), eA2 = __shfl(A2, ln - off);
    if (ln >= off) {
      A0 = eA0 + A0 + 0.5f * (e0 * d1 - e1 * d0);
      A1 = eA1 + A1 + 0.5f * (e0 * d2 - e2 * d0);
      A2 = eA2 + A2 + 0.5f * (e1 * d2 - e2 * d1);
      d0 += e0; d1 += e1; d2 += e2;
    }
  }
  if (ln == 63) {
    wtot[wv][0] = d0; wtot[wv][1] = d1; wtot[wv][2] = d2;
    wtot[wv][3] = A0; wtot[wv][4] = A1; wtot[wv][5] = A2;
  }
  __syncthreads();

  // wave-exclusive prefix (<=3 serial combines)
  float P0 = 0.f, P1 = 0.f, P2 = 0.f, PA0 = 0.f, PA1 = 0.f, PA2 = 0.f;
  for (int w = 0; w < wv; ++w) {
    float t0 = wtot[w][0], t1 = wtot[w][1], t2 = wtot[w][2];
    PA0 = PA0 + wtot[w][3] + 0.5f * (P0 * t1 - P1 * t0);
    PA1 = PA1 + wtot[w][4] + 0.5f * (P0 * t2 - P2 * t0);
    PA2 = PA2 + wtot[w][5] + 0.5f * (P1 * t2 - P2 * t1);
    P0 += t0; P1 += t1; P2 += t2;
  }
  // lane-exclusive within wave
  float L0 = __shfl(d0, ln - 1), L1 = __shfl(d1, ln - 1), L2 = __shfl(d2, ln - 1);
  float LA0 = __shfl(A0, ln - 1), LA1 = __shfl(A1, ln - 1), LA2 = __shfl(A2, ln - 1);
  if (ln == 0) { L0 = L1 = L2 = LA0 = LA1 = LA2 = 0.f; }
  float bp0 = P0 + L0, bp1 = P1 + L1, bp2 = P2 + L2;
  float C0 = PA0 + LA0 + 0.5f * (P0 * L1 - P1 * L0);
  float C1 = PA1 + LA1 + 0.5f * (P0 * L2 - P2 * L0);
  float C2 = PA2 + LA2 + 0.5f * (P1 * L2 - P2 * L1);

  // ---- absolute re-walk of own chunk: checkpoints + ends ----
  if (p0 <= 999) {
#pragma unroll
    for (int i = 0; i < 4; ++i) {
      int p = p0 + i;
      if (p > 999) break;
      float n0 = bp0 + zs[p * 3 + 0] * scale;
      float n1 = bp1 + zs[p * 3 + 1] * scale;
      float n2 = bp2 + zs[p * 3 + 2] * scale;
      C0 += 0.5f * (bp0 * n1 - bp1 * n0);
      C1 += 0.5f * (bp0 * n2 - bp2 * n0);
      C2 += 0.5f * (bp1 * n2 - bp2 * n1);
      bp0 = n0; bp1 = n1; bp2 = n2;
      if (p % 50 == 0) {
        int s = p / 50;
        Cs[s][0] = C0; Cs[s][1] = C1; Cs[s][2] = C2;
      }
      int k = myfe[i];
      if (k >= 0) {
        earr[k][0] = bp0; earr[k][1] = bp1; earr[k][2] = bp2;
        earr[k][3] = C0;  earr[k][4] = C1;  earr[k][5] = C2;
      }
    }
  }
  __syncthreads();

  // ---- gather: 63 ends -> lsh[t=k+1][b], thread 63 zeros t=0 ----
  if (tid < 63) {
    int s = sidx[tid];
    half8 v = {};
    v[0] = (f16)earr[tid][0]; v[1] = (f16)earr[tid][1]; v[2] = (f16)earr[tid][2];
    v[3] = (f16)(earr[tid][3] - Cs[s][0]);
    v[4] = (f16)(earr[tid][4] - Cs[s][1]);
    v[5] = (f16)(earr[tid][5] - Cs[s][2]);
    half8 zz = {};
    half8* d = (half8*)(lsh + ((size_t)(tid + 1) * BATCH + b) * 64);
    d[0] = v;
#pragma unroll
    for (int q = 1; q < 8; ++q) d[q] = zz;
  } else if (tid == 63) {
    half8 zz = {};
    half8* d = (half8*)(lsh + (size_t)b * 64);
#pragma unroll
    for (int q = 0; q < 8; ++q) d[q] = zz;
  }
}

// ---------------------------------------------------------------------------
// f32 -> f16 weight convert with K zero-padding.  dst[N][Kd], src[N][Ks].
// ---------------------------------------------------------------------------
__global__ __launch_bounds__(256)
void cvt_w(const float* __restrict__ src, ushort* __restrict__ dst,
           int N, int Ks, int Kd) {
  int i = blockIdx.x * 256 + threadIdx.x;
  int nblk = Kd >> 3;
  if (i >= N * nblk) return;
  int row = i / nblk, k = (i - row * nblk) * 8;
  half8 v;
#pragma unroll
  for (int j = 0; j < 8; ++j) {
    int kk = k + j;
    float f = (kk < Ks) ? src[(size_t)row * Ks + kk] : 0.f;
    v[j] = (f16)f;
  }
  *(half8*)&dst[(size_t)row * Kd + k] = v;
}

// ---------------------------------------------------------------------------
// fp16 MFMA GEMM: 128x128 tile, BK=64, 4 waves (2x2), 16x16x32 f16 MFMA.
// A-op = W rows (n), B-op = X rows (m). L1 mode: X = [carry(Hg/zero) | lsh].
// (validated round 2)
// ---------------------------------------------------------------------------
template<int ACT, int L1>
__global__ __launch_bounds__(256)
void gemm_h(const ushort* __restrict__ A, int lda, int nk,
            const ushort* __restrict__ Hg, const ushort* __restrict__ zeroh,
            const ushort* __restrict__ lsh, int chunk0, SegMap seg,
            const ushort* __restrict__ W, int ldw,
            const float* __restrict__ bias,
            ushort* __restrict__ C, int ldc) {
  __shared__ ushort lds[16384];            // 32KB: X[128][64] | W[128][64]
  char* ldsb = (char*)lds;
  const int tid = threadIdx.x;
  const int wv = tid >> 6, ln = tid & 63;
  const int bn0 = blockIdx.x * 128;
  const int br = blockIdx.y;
  const size_t gr0 = (size_t)br * 128;

  const ushort* abase = A;
  const ushort* lbase = nullptr;
  if (L1) {
    int t = chunk0 + (br >> 3);
    int sj = seg.idx[t];
    abase = (sj < 0) ? zeroh : Hg + (size_t)sj * (BATCH * HID);
    lbase = lsh + (size_t)t * BATCH * 64;
  }

  f32x4 acc[4][4];
#pragma unroll
  for (int mi = 0; mi < 4; ++mi)
#pragma unroll
    for (int ni = 0; ni < 4; ++ni) acc[mi][ni] = (f32x4){0.f, 0.f, 0.f, 0.f};

  const int xr0 = (wv >> 1) * 64, nr0 = (wv & 1) * 64;
  const int l15 = ln & 15, l4 = ln >> 4;

  for (int kt = 0; kt < nk; ++kt) {
    // ---- stage X tile ----
#pragma unroll
    for (int i = 0; i < 4; ++i) {
      int q = (i * 4 + wv) * 64 + ln;
      int r = q >> 3, sl = q & 7, ss = sl ^ (r & 7);
      const ushort* src;
      if (L1) {
        int b_ = ((br & 7) << 7) + r;
        if (kt < 8) src = abase + (size_t)b_ * HID + kt * 64 + ss * 8;
        else        src = lbase + (size_t)b_ * 64 + ss * 8;
      } else {
        src = A + (gr0 + r) * (size_t)lda + kt * 64 + ss * 8;
      }
      __builtin_amdgcn_global_load_lds(
          (const __attribute__((address_space(1))) unsigned int*)src,
          (__attribute__((address_space(3))) unsigned int*)(ldsb + (i * 4 + wv) * 1024),
          16, 0, 0);
    }
    // ---- stage W tile ----
#pragma unroll
    for (int i = 0; i < 4; ++i) {
      int q = (i * 4 + wv) * 64 + ln;
      int r = q >> 3, sl = q & 7, ss = sl ^ (r & 7);
      const ushort* src = W + (size_t)(bn0 + r) * ldw + kt * 64 + ss * 8;
      __builtin_amdgcn_global_load_lds(
          (const __attribute__((address_space(1))) unsigned int*)src,
          (__attribute__((address_space(3))) unsigned int*)(ldsb + 16384 + (i * 4 + wv) * 1024),
          16, 0, 0);
    }
    __syncthreads();
#pragma unroll
    for (int kk = 0; kk < 2; ++kk) {
      half8 xf[4], wf[4];
#pragma unroll
      for (int mi = 0; mi < 4; ++mi) {
        int r = xr0 + mi * 16 + l15;
        int ss = (kk * 4 + l4) ^ (r & 7);
        xf[mi] = *(const half8*)(ldsb + r * 128 + ss * 16);
      }
#pragma unroll
      for (int ni = 0; ni < 4; ++ni) {
        int r = nr0 + ni * 16 + l15;
        int ss = (kk * 4 + l4) ^ (r & 7);
        wf[ni] = *(const half8*)(ldsb + 16384 + r * 128 + ss * 16);
      }
#pragma unroll
      for (int mi = 0; mi < 4; ++mi)
#pragma unroll
        for (int ni = 0; ni < 4; ++ni)
          acc[mi][ni] = __builtin_amdgcn_mfma_f32_16x16x32_f16(wf[ni], xf[mi], acc[mi][ni], 0, 0, 0);
    }
    __syncthreads();
  }
  // ---- epilogue: bias + act + f16 pack, 8B stores ----
#pragma unroll
  for (int mi = 0; mi < 4; ++mi) {
    size_t gm = gr0 + xr0 + mi * 16 + l15;
#pragma unroll
    for (int ni = 0; ni < 4; ++ni) {
      int gn = bn0 + nr0 + ni * 16 + l4 * 4;
      f32x4 a = acc[mi][ni];
      union { f16 h[4]; ushort4 u; } cv;
#pragma unroll
      for (int j = 0; j < 4; ++j) {
        float v = a[j] + bias[gn + j];
        if (ACT == 1) v = fmaxf(v, 0.f);
        else { float xc = fminf(fmaxf(v, -9.f), 9.f); float e = __expf(2.f * xc); v = (e - 1.f) / (e + 1.f); }
        cv.h[j] = (f16)v;
      }
      *(ushort4*)&C[gm * ldc + gn] = cv.u;
    }
  }
}

// ---------------------------------------------------------------------------
// out[b, chunk0+tl, :] = h[row,:] @ Wout^T   (h fp16). 4 lanes/row.
// ---------------------------------------------------------------------------
__global__ __launch_bounds__(256)
void out_k(const ushort* __restrict__ H, const float* __restrict__ Wout,
           float* __restrict__ out, int chunk0) {
  const int tid = threadIdx.x;
  const int lane4 = tid & 3;
  const int row = blockIdx.x * 64 + (tid >> 2);
  const int tl = row >> 10, b = row & 1023;
  const ushort* hb = H + (size_t)row * HID;
  float a0 = 0.f, a1 = 0.f, a2 = 0.f;
#pragma unroll 4
  for (int q = 0; q < 16; ++q) {
    int k = (q * 4 + lane4) * 8;
    half8 hv = *(const half8*)&hb[k];
#pragma unroll
    for (int j = 0; j < 8; ++j) {
      float h = (float)hv[j];
      a0 += h * Wout[k + j];
      a1 += h * Wout[512 + k + j];
      a2 += h * Wout[1024 + k + j];
    }
  }
  a0 += __shfl_xor(a0, 1); a0 += __shfl_xor(a0, 2);
  a1 += __shfl_xor(a1, 1); a1 += __shfl_xor(a1, 2);
  a2 += __shfl_xor(a2, 1); a2 += __shfl_xor(a2, 2);
  if (lane4 == 0) {
    float* o = out + ((size_t)b * WIN + chunk0 + tl) * 3;
    o[0] = a0; o[1] = a1; o[2] = a2;
  }
}

// ---------------------------------------------------------------------------
extern "C" void kernel_launch(void* const* d_in, const int* in_sizes, int n_in,
                              void* d_out, int out_size, void* d_ws, size_t ws_size,
                              hipStream_t stream) {
  (void)n_in; (void)out_size; (void)ws_size; (void)in_sizes;
  const float* z    = (const float*)d_in[0];
  const float* W1   = (const float*)d_in[1];
  const float* b1   = (const float*)d_in[2];
  const float* W2   = (const float*)d_in[3];
  const float* b2   = (const float*)d_in[4];
  const float* W3   = (const float*)d_in[5];
  const float* b3   = (const float*)d_in[6];
  const float* Wout = (const float*)d_in[7];
  float* out = (float*)d_out;

  // ---- replicate _static_schedule exactly (numpy linspace doubles) ----
  double tb[1000], tt[64], tu[20];
  {
    double sb = 1.0 / 999.0; for (int i = 0; i < 1000; ++i) tb[i] = i * sb; tb[999] = 1.0;
    double st = 1.0 / 63.0;  for (int k = 0; k < 64; ++k)  tt[k] = k * st;  tt[63] = 1.0;
    for (int j = 0; j < 20; ++j) tu[j] = tb[50 * j];
  }
  auto ssr = [](const double* a, int n, double v) -> int {
    int lo = 0, hi = n;
    while (lo < hi) { int mid = (lo + hi) >> 1; if (a[mid] <= v) lo = mid + 1; else hi = mid; }
    return lo - 1;
  };
  Sched sc; int gates[64];
  {
    int u_indices[20];
    for (int j = 0; j < 20; ++j) u_indices[j] = ssr(tb, 1000, tu[j]);
    double u_times[80]; int nut = 0; int last = -1;
    for (int k = 1; k < 64; ++k) {
      int it = ssr(tb, 1000, tt[k]);
      int iu = ssr(tu, 20, tt[k]); if (iu < 0) iu = 0;
      if (iu != last) { u_times[nut++] = tu[iu]; last = iu; }
      sc.starts[k - 1] = u_indices[iu];
      sc.ends[k - 1] = it;
    }
    u_times[nut++] = tt[63];
    int qh = 0;
    for (int k = 0; k < 64; ++k) {
      if (qh < nut && tt[k] >= u_times[qh]) { ++qh; gates[k] = 1; } else gates[k] = 0;
    }
  }
  // gated-step list + segment map (carry INPUT at step t = h of last gated < t)
  SegMap seg; int gsteps[64], ng = 0, jlast = -1;
  for (int t = 0; t < WIN; ++t) {
    seg.idx[t] = jlast;
    if (gates[t]) { gsteps[ng] = t; jlast = ng; ++ng; }
  }

  // ---- workspace carve ----
  char* p = (char*)d_ws;
  int* fe      = (int*)p;    p += 1024 * 4;                             // 4 KB
  int* sidx    = (int*)p;    p += 64 * 4;
  ushort* Hg16 = (ushort*)p; p += (size_t)22 * BATCH * HID * 2;         // 23 MB
  ushort* zeroh= (ushort*)p; p += (size_t)BATCH * HID * 2;              // 1 MB
  ushort* lsh  = (ushort*)p; p += (size_t)WIN * BATCH * 64 * 2;         // 8.4 MB
  ushort* W1h  = (ushort*)p; p += (size_t)HID * 576 * 2;
  ushort* W2h  = (ushort*)p; p += (size_t)HID * HID * 2;
  ushort* W3h  = (ushort*)p; p += (size_t)HID * HID * 2;
  ushort* ca1  = (ushort*)p; p += (size_t)BATCH * HID * 2;              // chain act
  ushort* ca2  = (ushort*)p; p += (size_t)BATCH * HID * 2;
  ushort* A2h  = (ushort*)p; p += (size_t)CHT * BATCH * HID * 2;        // 16.8 MB
  ushort* A3h  = (ushort*)p; p += (size_t)CHT * BATCH * HID * 2;

  hipMemsetAsync(zeroh, 0, (size_t)BATCH * HID * 2, stream);

  float scale = (float)std::sqrt(1.0 / 999.0);
  build_flags<<<1, 1024, 0, stream>>>(fe, sidx, sc);
  logsig_scan<<<BATCH, 256, 0, stream>>>(z, fe, sidx, lsh, scale);
  cvt_w<<<(HID * 72 + 255) / 256, 256, 0, stream>>>(W1, W1h, HID, KIN, 576);
  cvt_w<<<(HID * 64 + 255) / 256, 256, 0, stream>>>(W2, W2h, HID, HID, HID);
  cvt_w<<<(HID * 64 + 255) / 256, 256, 0, stream>>>(W3, W3h, HID, HID, HID);

  // ---- serial carry chain over gated steps, fp16 MFMA ----
  // seg.idx[gsteps[j]] == j-1, so the L1 path reads exactly the previous
  // gated h (or zeros for j=0) plus lsh[t=g].
  dim3 cg(4, 8), cb(256);
  for (int j = 0; j < ng - 1; ++j) {
    int g = gsteps[j];
    gemm_h<1, 1><<<cg, cb, 0, stream>>>(nullptr, HID, 9, Hg16, zeroh, lsh, g, seg,
                                        W1h, 576, b1, ca1, HID);
    gemm_h<1, 0><<<cg, cb, 0, stream>>>(ca1, HID, 8, Hg16, zeroh, lsh, 0, seg,
                                        W2h, HID, b2, ca2, HID);
    gemm_h<2, 0><<<cg, cb, 0, stream>>>(ca2, HID, 8, Hg16, zeroh, lsh, 0, seg,
                                        W3h, HID, b3, Hg16 + (size_t)j * BATCH * HID, HID);
  }

  // ---- parallel recompute of all 64 timesteps, fp16 MFMA, t-chunked ----
  dim3 gg(4, CHT * 8), gb(256);
  for (int c = 0; c < WIN / CHT; ++c) {
    int chunk0 = c * CHT;
    gemm_h<1, 1><<<gg, gb, 0, stream>>>(A2h, HID, 9, Hg16, zeroh, lsh, chunk0, seg,
                                        W1h, 576, b1, A2h, HID);
    gemm_h<1, 0><<<gg, gb, 0, stream>>>(A2h, HID, 8, Hg16, zeroh, lsh, 0, seg,
                                        W2h, HID, b2, A3h, HID);
    gemm_h<2, 0><<<gg, gb, 0, stream>>>(A3h, HID, 8, Hg16, zeroh, lsh, 0, seg,
                                        W3h, HID, b3, A2h, HID);
    out_k<<<CHT * BATCH / 64, 256, 0, stream>>>(A2h, Wout, out, chunk0);
  }
}